// Round 2
// baseline (345.446 us; speedup 1.0000x reference)
//
#include <hip/hip_runtime.h>

#define NN 100000
#define EE 1600000
#define ETOT 1700000          // EE + NN (self-loops appended)
#define FO 32
#define DTOT 3200000          // NN*FO dropout elements

// ---------------- threefry2x32 with key (0,1) = jax.random.key(1) -------
__device__ __forceinline__ unsigned rotl32(unsigned x, unsigned r) {
    return (x << r) | (x >> (32u - r));
}

__device__ __forceinline__ void threefry2x32_01(unsigned x0, unsigned x1,
                                                unsigned& y0, unsigned& y1) {
    const unsigned ks0 = 0u, ks1 = 1u, ks2 = 0x1BD11BDBu; // 0^1^0x1BD11BDA
    x0 += ks0; x1 += ks1;
#define TF_R(r) { x0 += x1; x1 = rotl32(x1, (r)); x1 ^= x0; }
    TF_R(13) TF_R(15) TF_R(26) TF_R(6)   x0 += ks1; x1 += ks2 + 1u;
    TF_R(17) TF_R(29) TF_R(16) TF_R(24)  x0 += ks2; x1 += ks0 + 2u;
    TF_R(13) TF_R(15) TF_R(26) TF_R(6)   x0 += ks0; x1 += ks1 + 3u;
    TF_R(17) TF_R(29) TF_R(16) TF_R(24)  x0 += ks1; x1 += ks2 + 4u;
    TF_R(13) TF_R(15) TF_R(26) TF_R(6)   x0 += ks2; x1 += ks0 + 5u;
#undef TF_R
    y0 = x0; y1 = x1;
}

// ---------------- K0: detect edge_index storage width -------------------
// int64 data with values < 2^31: every odd int32 word is 0. For int32 data
// the odd words are genuine node ids — P(first 4096 all zero) ~ 0.
__global__ __launch_bounds__(256) void k_detect(const unsigned* __restrict__ ei,
                                                unsigned* __restrict__ flag) {
    __shared__ unsigned red[256];
    unsigned v = 0;
    for (int i = threadIdx.x; i < 4096; i += 256) v |= ei[2 * i + 1];
    red[threadIdx.x] = v;
    __syncthreads();
    for (int s = 128; s; s >>= 1) {
        if (threadIdx.x < s) red[threadIdx.x] |= red[threadIdx.x + s];
        __syncthreads();
    }
    if (threadIdx.x == 0) *flag = (red[0] == 0u) ? 1u : 0u;  // 1 => int64
}

__device__ __forceinline__ int load_idx(const int* __restrict__ ei,
                                        int logical, unsigned wide) {
    // little-endian: low word of int64 element k is int32 word 2k
    return ei[wide ? (logical << 1) : logical];
}

// ---------------- K1: h = x @ W, fused a_src/a_dst ----------------------
__global__ __launch_bounds__(256) void k_gemm(
    const float* __restrict__ x, const float* __restrict__ W,
    const float* __restrict__ att_s, const float* __restrict__ att_d,
    float* __restrict__ h, float* __restrict__ a_s, float* __restrict__ a_d)
{
    __shared__ float Ws[256 * 32];     // 32 KB
    __shared__ float xs[32 * 132];     // 16.9 KB
    const int tid = threadIdx.x;

    #pragma unroll
    for (int i = 0; i < 8; ++i) {      // stage W once (coalesced float4)
        int idx = i * 1024 + tid * 4;
        *reinterpret_cast<float4*>(Ws + idx) =
            *reinterpret_cast<const float4*>(W + idx);
    }

    const int j4 = tid & 7;            // colgroup
    const int rl = tid >> 3;           // local row 0..31
    const int c0 = j4 * 4;
    const float4 avs = *reinterpret_cast<const float4*>(att_s + c0);
    const float4 avd = *reinterpret_cast<const float4*>(att_d + c0);

    for (int tile = blockIdx.x; tile < (NN / 32); tile += gridDim.x) {
        const int row0 = tile * 32;
        float4 acc = make_float4(0.f, 0.f, 0.f, 0.f);

        for (int kc = 0; kc < 256; kc += 128) {
            __syncthreads();           // protects xs reuse (and W on 1st pass)
            #pragma unroll
            for (int i = 0; i < 4; ++i) {          // stage 32x128 chunk
                int l = i * 1024 + tid * 4;        // 0..4092
                int r = l >> 7, c = l & 127;
                *reinterpret_cast<float4*>(xs + r * 132 + c) =
                    *reinterpret_cast<const float4*>(
                        x + (size_t)(row0 + r) * 256 + kc + c);
            }
            __syncthreads();
            const float* xr = xs + rl * 132;
            #pragma unroll 4
            for (int k0 = 0; k0 < 128; k0 += 4) {
                float4 xv = *reinterpret_cast<const float4*>(xr + k0);
                #pragma unroll
                for (int q = 0; q < 4; ++q) {
                    float xq = (q == 0) ? xv.x : (q == 1) ? xv.y
                             : (q == 2) ? xv.z : xv.w;
                    float4 wv = *reinterpret_cast<const float4*>(
                        Ws + (kc + k0 + q) * 32 + c0);
                    acc.x = fmaf(xq, wv.x, acc.x);
                    acc.y = fmaf(xq, wv.y, acc.y);
                    acc.z = fmaf(xq, wv.z, acc.z);
                    acc.w = fmaf(xq, wv.w, acc.w);
                }
            }
        }
        const int row = row0 + rl;
        *reinterpret_cast<float4*>(h + (size_t)row * 32 + c0) = acc;
        float v1 = acc.x * avs.x + acc.y * avs.y + acc.z * avs.z + acc.w * avs.w;
        float v2 = acc.x * avd.x + acc.y * avd.y + acc.z * avd.z + acc.w * avd.w;
        #pragma unroll
        for (int off = 4; off; off >>= 1) {    // reduce over 8-lane colgroups
            v1 += __shfl_xor(v1, off, 8);
            v2 += __shfl_xor(v2, off, 8);
        }
        if (j4 == 0) { a_s[row] = v1; a_d[row] = v2; }
    }
}

// ---------------- K2: edge weights + denom ------------------------------
__global__ __launch_bounds__(256) void k_edge1(
    const int* __restrict__ ei, const unsigned* __restrict__ flag,
    const float* __restrict__ a_s, const float* __restrict__ a_d,
    float* __restrict__ wE, float* __restrict__ den)
{
    int e = blockIdx.x * 256 + threadIdx.x;
    if (e >= ETOT) return;
    const unsigned wide = *flag;
    int s, d;
    if (e < EE) { s = load_idx(ei, e, wide); d = load_idx(ei, EE + e, wide); }
    else        { s = d = e - EE; }
    float al = a_s[s] + a_d[d];
    al = (al >= 0.f) ? al : 0.2f * al;     // leaky_relu(0.2)
    float w = expf(al);                    // max-shift skipped: ratio-invariant
    wE[e] = w;
    atomicAdd(&den[d], w);
}

// ---------------- K3: weighted scatter-add (32 lanes/edge) --------------
__global__ __launch_bounds__(256) void k_edge2(
    const int* __restrict__ ei, const unsigned* __restrict__ flag,
    const float* __restrict__ wE, const float* __restrict__ den,
    const float* __restrict__ h, float* __restrict__ out)
{
    int gid = blockIdx.x * 256 + threadIdx.x;   // < 54.4M
    int e = gid >> 5;
    if (e >= ETOT) return;
    int j = gid & 31;
    const unsigned wide = *flag;
    int s, d;
    if (e < EE) { s = load_idx(ei, e, wide); d = load_idx(ei, EE + e, wide); }
    else        { s = d = e - EE; }
    float coef = wE[e] / den[d];
    atomicAdd(&out[(size_t)d * 32 + j], coef * h[(size_t)s * 32 + j]);
}

// ---------------- K4: bias + ReLU + partitionable-threefry dropout ------
// jax >= 0.4.x default: jax_threefry_partitionable=True. 32-bit draws are
// elementwise: counter (hi64(i)=0, lo64(i)=i), bits = y0 ^ y1.
// uniform<0.5  <=>  bit31(bits)==0.
__global__ __launch_bounds__(256) void k_final(
    const float* __restrict__ bias, float* __restrict__ out)
{
    int t = blockIdx.x * 256 + threadIdx.x;     // [0, DTOT)
    if (t >= DTOT) return;
    unsigned y0, y1;
    threefry2x32_01(0u, (unsigned)t, y0, y1);
    unsigned bits = y0 ^ y1;
    float v = fmaxf(out[t] + bias[t & 31], 0.f);
    out[t] = (bits >> 31) ? 0.f : v * 2.f;      // keep iff bit31==0
}

extern "C" void kernel_launch(void* const* d_in, const int* in_sizes, int n_in,
                              void* d_out, int out_size, void* d_ws, size_t ws_size,
                              hipStream_t stream) {
    const float* x     = (const float*)d_in[0];
    const float* W     = (const float*)d_in[1];
    const float* att_s = (const float*)d_in[2];
    const float* att_d = (const float*)d_in[3];
    const float* bias  = (const float*)d_in[4];
    const int*   ei    = (const int*)d_in[5];
    float* out = (float*)d_out;

    // ws layout (floats): h[NN*32] | a_s[NN] | a_d[NN] | den[NN] | wE[ETOT] | flag
    float* h   = (float*)d_ws;
    float* a_s = h + (size_t)NN * FO;
    float* a_d = a_s + NN;
    float* den = a_d + NN;
    float* wE  = den + NN;
    unsigned* flag = (unsigned*)(wE + ETOT);

    hipMemsetAsync(den, 0, (size_t)NN * sizeof(float), stream);
    hipMemsetAsync(out, 0, (size_t)out_size * sizeof(float), stream);

    k_detect<<<1, 256, 0, stream>>>((const unsigned*)ei, flag);
    k_gemm<<<1024, 256, 0, stream>>>(x, W, att_s, att_d, h, a_s, a_d);
    k_edge1<<<(ETOT + 255) / 256, 256, 0, stream>>>(ei, flag, a_s, a_d, wE, den);
    k_edge2<<<(int)(((size_t)ETOT * 32) / 256), 256, 0, stream>>>(ei, flag, wE, den, h, out);
    k_final<<<DTOT / 256, 256, 0, stream>>>(bias, out);
}